// Round 6
// baseline (30046.304 us; speedup 1.0000x reference)
//
#include <hip/hip_runtime.h>
#include <stdint.h>

typedef unsigned short ushort_t;
typedef _Float16 f16_t;
typedef __attribute__((ext_vector_type(2))) _Float16 half2;
typedef __attribute__((ext_vector_type(8))) _Float16 half8;
typedef __attribute__((ext_vector_type(4))) float f32x4;

#define T_SEQ 4096
#define IN_SZ 512
#define H1 1024
#define H2 2048
#define G1 (4*H1)   // 4096
#define G2 (4*H2)   // 8192
#define OUT_SZ 512
#define L1OUT 1024

#define SENT 0xAAAAAAAAu

__device__ __forceinline__ float f16_val(ushort_t v) {
    union { ushort_t u; _Float16 h; } x; x.u = v; return (float)x.h;
}
__device__ __forceinline__ half2 u2h(uint32_t w) {
    union { uint32_t u; half2 h; } x; x.u = w; return x.h;
}
__device__ __forceinline__ uint32_t pack_f16(float a, float b) {
    auto h = __builtin_amdgcn_cvt_pkrtz(a, b);   // __fp16 ext_vector(2) on gfx950
    union { decltype(h) h; uint32_t u; } x; x.h = h; return x.u;
}
// fast gate math
__device__ __forceinline__ float fsig(float x) {
    return __builtin_amdgcn_rcpf(1.0f + __expf(-x));
}
__device__ __forceinline__ float ftanh(float x) {
    return 1.0f - 2.0f * __builtin_amdgcn_rcpf(__expf(2.0f * x) + 1.0f);
}

// 2 MACs: acc += w·h for one packed f16 pair
__device__ __forceinline__ void dot2(float& acc, uint32_t w, uint32_t h) {
#if defined(__has_builtin) && __has_builtin(__builtin_amdgcn_fdot2)
    acc = __builtin_amdgcn_fdot2(u2h(w), u2h(h), acc, false);
#else
    half2 a = u2h(w), b = u2h(h);
    acc = fmaf((float)a.x, (float)b.x, acc);
    acc = fmaf((float)a.y, (float)b.y, acc);
#endif
}
#define DOT4(ACC, W, Hv) do { dot2(ACC, (W).x, (Hv).x); dot2(ACC, (W).y, (Hv).y); \
                              dot2(ACC, (W).z, (Hv).z); dot2(ACC, (W).w, (Hv).w); } while (0)

__device__ __forceinline__ uint64_t ald64(const uint64_t* p) {
    return __hip_atomic_load(p, __ATOMIC_RELAXED, __HIP_MEMORY_SCOPE_AGENT);
}
__device__ __forceinline__ int bad64(uint64_t q) {
    return (int)(((uint32_t)q == SENT) | ((uint32_t)(q >> 32) == SENT));
}

// ---------------- f32 -> f16 conversion ----------------
__global__ __launch_bounds__(256) void cvt_f16_kernel(const float* __restrict__ in,
                                                      f16_t* __restrict__ out, int n) {
    int i = blockIdx.x * 256 + threadIdx.x;
    int stride = gridDim.x * 256;
    for (; i < n; i += stride) out[i] = (f16_t)in[i];
}

// ---------------- f16 MFMA GEMM: C[M,N] = A[M,K] * B[N,K]^T + bias_a + bias_b, f16 out ----------
__global__ __launch_bounds__(256) void gemm_bt_kernel(const f16_t* __restrict__ A,
                                                      const f16_t* __restrict__ B,
                                                      f16_t* __restrict__ Cb,
                                                      const float* __restrict__ bias_a,
                                                      const float* __restrict__ bias_b,
                                                      int M, int N, int K) {
    int tid  = threadIdx.x;
    int wave = tid >> 6;
    int lane = tid & 63;
    int l15  = lane & 15;
    int quad = lane >> 4;
    int m0 = blockIdx.y * 64 + wave * 16;
    int n0 = blockIdx.x * 64;

    const f16_t* pa = A + (size_t)(m0 + l15) * K + quad * 8;
    f32x4 acc[4];
    #pragma unroll
    for (int i = 0; i < 4; ++i) acc[i] = (f32x4){0.f, 0.f, 0.f, 0.f};

    for (int kc = 0; kc < K; kc += 32) {
        half8 a = *(const half8*)(pa + kc);
        #pragma unroll
        for (int nf = 0; nf < 4; ++nf) {
            const f16_t* pb = B + (size_t)(n0 + nf * 16 + l15) * K + quad * 8 + kc;
            half8 b = *(const half8*)pb;
            acc[nf] = __builtin_amdgcn_mfma_f32_16x16x32_f16(a, b, acc[nf], 0, 0, 0);
        }
    }

    int rbase = quad * 4;
    #pragma unroll
    for (int nf = 0; nf < 4; ++nf) {
        int n = n0 + nf * 16 + l15;
        float bb = bias_a[n] + bias_b[n];
        #pragma unroll
        for (int r = 0; r < 4; ++r) {
            int m = m0 + rbase + r;
            Cb[(size_t)m * N + n] = (f16_t)(acc[nf][r] + bb);
        }
    }
}

// ---------------- Fused 2-layer LSTM: intra-block role split ----------------
// 256 blocks x 256 threads (1 block/CU, persistent). Block b owns h1 units [4b,4b+4),
// h2 units [8b,8b+8). Waves 0-1 = ROLE1 (h1 chain + pre2), waves 2-3 = ROLE2 (h2
// chain). ONE block barrier per iteration; the two chains' polls + dot phases overlap
// in time (step = max(role1, role2) instead of the serial A->B->pre2->B'->C sum).
// Iteration i:
//  ROLE1 (wave w, units 2w,2w+1): wave-direct poll comm1[i-1] (each lane loads its
//    dot slice; no LDS staging, no extra barrier) -> whh1 dots -> h1[i] publish
//    -> pre2[i-1] = wih2·h1[i-1] -> LDS slot (i-1)&1.
//  ROLE2 (group gi, units 2gi,2gi+1): compute h2[i-2] from h2b[(i-1)&1] (=comm2[i-3],
//    staged last iter) + pre2b[i&1] (=pre2[i-2]) -> publish; THEN poll comm2[i-2] and
//    stage h2b[i&1]. Publish-before-poll => deadlock-free (consumption is strictly
//    earlier-iteration or earlier-program-order data; induction over iterations).
// Weights: whh1(32KB)+wih2(64KB)+whh2 gate0(32KB) in LDS; whh2 gates1-3 streamed from
// L2 at point of use (rounds 4/5 proved this is ~free when scheduled there).
// comm f32, sentinel 0xAA, 64-bit polls, s_sleep pacing.
__global__ __launch_bounds__(256, 1) void fused_lstm_kernel(
        const f16_t* __restrict__ pre1,       // f16 [T, 4096]
        const ushort_t* __restrict__ whh1h,   // f16 bits [4096, 1024]
        const ushort_t* __restrict__ wih2h,   // f16 bits [8192, 1024]
        const ushort_t* __restrict__ whh2h,   // f16 bits [8192, 2048]
        const float* __restrict__ bih2,
        const float* __restrict__ bhh2,
        uint32_t* __restrict__ comm1,         // f32 bits [T, 1024], pre-poisoned 0xAA
        uint32_t* __restrict__ comm2,         // f32 bits [T, 2048], pre-poisoned 0xAA
        int T) {
    extern __shared__ char smem[];
    uint32_t* whh1_w = (uint32_t*)smem;             // [16][512]  f16-pair words (32KB)
    uint32_t* wih2_w = whh1_w + 16 * 512;           // [32][512]  (64KB)
    uint32_t* whh2_w = wih2_w + 32 * 512;           // [8][1024]  gate0 (32KB)
    uint32_t* h2b    = whh2_w + 8 * 1024;           // [2][1024]  packed h2 (8KB)
    float*    pre2b  = (float*)(h2b + 2 * 1024);    // [2][32]    pre2 handoff (256B)

    int tid = threadIdx.x;
    int blk = blockIdx.x;
    int wid = tid >> 6;          // wave id 0..3
    int ln  = tid & 63;
    int ln2 = ln & 31;

    // ---- stage resident weights into LDS (all 256 threads; layouts as before) ----
    #pragma unroll
    for (int i = 0; i < 8; ++i) {            // whh1: 16 rows x 128 uint4
        int idx = tid + i * 256, r = idx >> 7, ch = idx & 127;
        size_t R = (size_t)(r & 3) * H1 + blk * 4 + (r >> 2);
        *(uint4*)&whh1_w[r * 512 + ch * 4] = *(const uint4*)(whh1h + R * H1 + ch * 8);
    }
    #pragma unroll
    for (int i = 0; i < 16; ++i) {           // wih2: 32 rows x 128 uint4
        int idx = tid + i * 256, r = idx >> 7, ch = idx & 127;
        size_t R = (size_t)(r & 3) * H2 + blk * 8 + (r >> 2);
        *(uint4*)&wih2_w[r * 512 + ch * 4] = *(const uint4*)(wih2h + R * H1 + ch * 8);
    }
    #pragma unroll
    for (int i = 0; i < 8; ++i) {            // whh2 gate0: 8 rows x 256 uint4
        int idx = tid + i * 256, r = idx >> 8, ch = idx & 255;
        size_t R = (size_t)(blk * 8 + r);
        *(uint4*)&whh2_w[r * 1024 + ch * 4] = *(const uint4*)(whh2h + R * H2 + ch * 8);
    }
    __syncthreads();

    // ---- role-persistent state ----
    float c1a = 0.f, c1b = 0.f;              // role1 (lane0 of waves 0,1): cells of 2 h1 units
    float c2a = 0.f, c2b = 0.f;              // role2 (ln2==0): cells of 2 h2 units
    int gi = (wid - 2) * 2 + (ln >> 5);      // role2 group 0..3 (valid when wid>=2)
    float b2gA[4] = {0,0,0,0}, b2gB[4] = {0,0,0,0};
    if (wid >= 2) {
        int U0 = blk * 8 + gi * 2, U1 = U0 + 1;
        #pragma unroll
        for (int g = 0; g < 4; ++g) {
            b2gA[g] = bih2[g * H2 + U0] + bhh2[g * H2 + U0];
            b2gB[g] = bih2[g * H2 + U1] + bhh2[g * H2 + U1];
        }
    }

    for (int i = 0; i <= T + 1; ++i) {
        if (wid < 2) {
            // ================= ROLE 1: h1 chain + pre2 =================
            int w = wid;
            // pre1 row i for this wave's 2 units (lane0)
            float pcA[4] = {0,0,0,0}, pcB[4] = {0,0,0,0};
            if (ln == 0 && i < T) {
                #pragma unroll
                for (int g = 0; g < 4; ++g) {
                    pcA[g] = f16_val(((const ushort_t*)pre1)[(size_t)i * G1 + g * H1 + blk * 4 + w * 2]);
                    pcB[g] = f16_val(((const ushort_t*)pre1)[(size_t)i * G1 + g * H1 + blk * 4 + w * 2 + 1]);
                }
            }
            // wave-direct poll of comm1[i-1]: lane ln needs f32 [ln*8..+7] and [512+ln*8..+7]
            uint4 hA = {0,0,0,0}, hB = {0,0,0,0};
            bool havePoll = (i >= 1 && i <= T);
            if (havePoll) {
                const uint64_t* p0 = (const uint64_t*)(comm1 + (size_t)(i - 1) * H1) + ln * 4;
                const uint64_t* p1 = (const uint64_t*)(comm1 + (size_t)(i - 1) * H1 + 512) + ln * 4;
                uint64_t q[8];
                for (;;) {
                    #pragma unroll
                    for (int k = 0; k < 4; ++k) { q[k] = ald64(p0 + k); q[4 + k] = ald64(p1 + k); }
                    int bad = 0;
                    #pragma unroll
                    for (int k = 0; k < 8; ++k) bad |= bad64(q[k]);
                    if (!__any(bad)) break;
                    __builtin_amdgcn_s_sleep(1);
                }
                uint32_t pw[8];
                #pragma unroll
                for (int k = 0; k < 8; ++k) {
                    union { uint64_t q; float f[2]; } x; x.q = q[k];
                    pw[k] = pack_f16(x.f[0], x.f[1]);
                }
                hA.x = pw[0]; hA.y = pw[1]; hA.z = pw[2]; hA.w = pw[3];
                hB.x = pw[4]; hB.y = pw[5]; hB.z = pw[6]; hB.w = pw[7];
            }
            // h1[i] = gates(whh1·h1[i-1] + pre1[i]) for 2 units
            if (i < T) {
                float a[8] = {0,0,0,0,0,0,0,0};
                if (i >= 1) {
                    #pragma unroll
                    for (int u2 = 0; u2 < 2; ++u2) {
                        #pragma unroll
                        for (int g = 0; g < 4; ++g) {
                            int r = (w * 2 + u2) * 4 + g;
                            uint4 w0 = *(const uint4*)&whh1_w[r * 512 + ln * 4];
                            uint4 w1 = *(const uint4*)&whh1_w[r * 512 + ln * 4 + 256];
                            DOT4(a[u2 * 4 + g], w0, hA);
                            DOT4(a[u2 * 4 + g], w1, hB);
                        }
                    }
                }
                #pragma unroll
                for (int off = 32; off > 0; off >>= 1) {
                    #pragma unroll
                    for (int k = 0; k < 8; ++k) a[k] += __shfl_down(a[k], off, 64);
                }
                if (ln == 0) {
                    float iv = fsig(pcA[0] + a[0]);
                    float fv = fsig(pcA[1] + a[1]);
                    float gv = ftanh(pcA[2] + a[2]);
                    float ov = fsig(pcA[3] + a[3]);
                    c1a = fv * c1a + iv * gv;
                    float h = ov * ftanh(c1a);
                    union { float f; uint32_t u; } x; x.f = h;
                    __hip_atomic_store(&comm1[(size_t)i * H1 + blk * 4 + w * 2], x.u,
                                       __ATOMIC_RELAXED, __HIP_MEMORY_SCOPE_AGENT);
                    iv = fsig(pcB[0] + a[4]);
                    fv = fsig(pcB[1] + a[5]);
                    gv = ftanh(pcB[2] + a[6]);
                    ov = fsig(pcB[3] + a[7]);
                    c1b = fv * c1b + iv * gv;
                    h = ov * ftanh(c1b);
                    x.f = h;
                    __hip_atomic_store(&comm1[(size_t)i * H1 + blk * 4 + w * 2 + 1], x.u,
                                       __ATOMIC_RELAXED, __HIP_MEMORY_SCOPE_AGENT);
                }
            }
            // pre2[i-1] = 16 wih2 rows (this wave) · h1[i-1] -> LDS slot (i-1)&1
            if (havePoll) {
                float pv[16];
                #pragma unroll
                for (int d = 0; d < 16; ++d) pv[d] = 0.f;
                #pragma unroll
                for (int d = 0; d < 16; ++d) {
                    int r = w * 16 + d;
                    uint4 w0 = *(const uint4*)&wih2_w[r * 512 + ln * 4];
                    uint4 w1 = *(const uint4*)&wih2_w[r * 512 + ln * 4 + 256];
                    DOT4(pv[d], w0, hA);
                    DOT4(pv[d], w1, hB);
                }
                #pragma unroll
                for (int off = 32; off > 0; off >>= 1) {
                    #pragma unroll
                    for (int d = 0; d < 16; ++d) pv[d] += __shfl_down(pv[d], off, 64);
                }
                if (ln == 0) {
                    float* dst = pre2b + ((i - 1) & 1) * 32 + w * 16;
                    #pragma unroll
                    for (int d = 0; d < 16; ++d) dst[d] = pv[d];
                }
            }
        } else {
            // ================= ROLE 2: h2 chain =================
            int u0 = gi * 2, u1v = gi * 2 + 1;
            // STEP 1: h2[i-2] = gates(whh2·h2[i-3] + pre2[i-2]); publish
            if (i >= 2) {
                int t = i - 2;
                float acc[8] = {0,0,0,0,0,0,0,0};
                if (i >= 3) {
                    const uint32_t* h2p = h2b + ((i - 1) & 1) * 1024;
                    #pragma unroll
                    for (int j = 0; j < 8; ++j) {
                        uint4 hx = *(const uint4*)&h2p[ln2 * 4 + j * 128];
                        uint4 wa = *(const uint4*)&whh2_w[u0 * 1024 + ln2 * 4 + j * 128];
                        uint4 wb = *(const uint4*)&whh2_w[u1v * 1024 + ln2 * 4 + j * 128];
                        DOT4(acc[0], wa, hx);
                        DOT4(acc[4], wb, hx);
                        #pragma unroll
                        for (int g = 1; g < 4; ++g) {
                            uint4 ga = *(const uint4*)(whh2h + ((size_t)g * H2 + blk * 8 + u0) * H2 + ln2 * 8 + j * 256);
                            uint4 gb = *(const uint4*)(whh2h + ((size_t)g * H2 + blk * 8 + u1v) * H2 + ln2 * 8 + j * 256);
                            DOT4(acc[g], ga, hx);
                            DOT4(acc[4 + g], gb, hx);
                        }
                    }
                }
                #pragma unroll
                for (int off = 16; off > 0; off >>= 1) {
                    #pragma unroll
                    for (int k = 0; k < 8; ++k) acc[k] += __shfl_down(acc[k], off, 32);
                }
                if (ln2 == 0) {
                    const float* pp = pre2b + (i & 1) * 32;     // slot (i-2)&1 == i&1
                    float iv = fsig(pp[u0 * 4 + 0] + b2gA[0] + acc[0]);
                    float fv = fsig(pp[u0 * 4 + 1] + b2gA[1] + acc[1]);
                    float gv = ftanh(pp[u0 * 4 + 2] + b2gA[2] + acc[2]);
                    float ov = fsig(pp[u0 * 4 + 3] + b2gA[3] + acc[3]);
                    c2a = fv * c2a + iv * gv;
                    float h = ov * ftanh(c2a);
                    union { float f; uint32_t u; } x; x.f = h;
                    __hip_atomic_store(&comm2[(size_t)t * H2 + blk * 8 + u0], x.u,
                                       __ATOMIC_RELAXED, __HIP_MEMORY_SCOPE_AGENT);
                    iv = fsig(pp[u1v * 4 + 0] + b2gB[0] + acc[4]);
                    fv = fsig(pp[u1v * 4 + 1] + b2gB[1] + acc[5]);
                    gv = ftanh(pp[u1v * 4 + 2] + b2gB[2] + acc[6]);
                    ov = fsig(pp[u1v * 4 + 3] + b2gB[3] + acc[7]);
                    c2b = fv * c2b + iv * gv;
                    h = ov * ftanh(c2b);
                    x.f = h;
                    __hip_atomic_store(&comm2[(size_t)t * H2 + blk * 8 + u1v], x.u,
                                       __ATOMIC_RELAXED, __HIP_MEMORY_SCOPE_AGENT);
                }
            }
            // STEP 2: poll comm2[i-2] (others publish it in their STEP 1 this iter)
            //         and stage packed f16 into h2b[i&1] for next iteration's dots
            if (i >= 2 && i <= T) {
                int t2 = tid - 128;   // 0..127: stages f32 [t2*16..+15] -> words [t2*8..+7]
                const uint64_t* p = (const uint64_t*)(comm2 + (size_t)(i - 2) * H2) + t2 * 8;
                uint64_t q[8];
                for (;;) {
                    #pragma unroll
                    for (int k = 0; k < 8; ++k) q[k] = ald64(p + k);
                    int bad = 0;
                    #pragma unroll
                    for (int k = 0; k < 8; ++k) bad |= bad64(q[k]);
                    if (!__any(bad)) break;
                    __builtin_amdgcn_s_sleep(1);
                }
                uint32_t* d = h2b + (i & 1) * 1024 + t2 * 8;
                #pragma unroll
                for (int k = 0; k < 8; ++k) {
                    union { uint64_t q; float f[2]; } x; x.q = q[k];
                    d[k] = pack_f16(x.f[0], x.f[1]);
                }
            }
        }
        __syncthreads();   // one barrier/iteration: publishes pre2b + h2b slots
    }
}

// ---------------- small matvec ----------------
__global__ __launch_bounds__(256) void linear_vec_kernel(const float* __restrict__ W,
                                                         const float* __restrict__ bias,
                                                         const float* __restrict__ x,
                                                         float* __restrict__ out,
                                                         int N, int K) {
    int wave = threadIdx.x >> 6;
    int lane = threadIdx.x & 63;
    int j = blockIdx.x * 4 + wave;
    if (j >= N) return;
    const float* wr = W + (size_t)j * K;
    float s = 0.0f;
    for (int k = lane; k < K; k += 64) s += wr[k] * x[k];
    #pragma unroll
    for (int off = 32; off > 0; off >>= 1) s += __shfl_down(s, off, 64);
    if (lane == 0) out[j] = s + bias[j];
}

extern "C" void kernel_launch(void* const* d_in, const int* in_sizes, int n_in,
                              void* d_out, int out_size, void* d_ws, size_t ws_size,
                              hipStream_t stream) {
    const float* x_f    = (const float*)d_in[0];
    const float* wih1_f = (const float*)d_in[1];
    const float* whh1_f = (const float*)d_in[2];
    const float* bih1   = (const float*)d_in[3];
    const float* bhh1   = (const float*)d_in[4];
    const float* wih2_f = (const float*)d_in[5];
    const float* whh2_f = (const float*)d_in[6];
    const float* bih2   = (const float*)d_in[7];
    const float* bhh2   = (const float*)d_in[8];
    const float* wl1    = (const float*)d_in[9];
    const float* bl1    = (const float*)d_in[10];
    const float* wl2    = (const float*)d_in[11];
    const float* bl2    = (const float*)d_in[12];

    uint8_t* base = (uint8_t*)d_ws;
    size_t off = 0;
    auto alloc = [&](size_t bytes) { size_t o = off; off = (off + bytes + 255) & ~(size_t)255; return o; };

    size_t pre1_off  = alloc((size_t)T_SEQ * G1 * 2);   // f16 [T,4096]
    size_t comm1_off = alloc((size_t)T_SEQ * H1 * 4);   // f32 [T,1024]
    size_t comm2_off = alloc((size_t)T_SEQ * H2 * 4);   // f32 [T,2048]
    size_t whh1_off  = alloc((size_t)G1 * H1 * 2);
    size_t whh2_off  = alloc((size_t)G2 * H2 * 2);
    size_t wih1_off  = alloc((size_t)G1 * IN_SZ * 2);
    size_t wih2_off  = alloc((size_t)G2 * H1 * 2);
    size_t xb_off    = alloc((size_t)T_SEQ * IN_SZ * 2);
    size_t p1_off    = alloc((size_t)L1OUT * 4);

    f16_t*    pre1  = (f16_t*)(base + pre1_off);
    uint32_t* comm1 = (uint32_t*)(base + comm1_off);
    uint32_t* comm2 = (uint32_t*)(base + comm2_off);
    ushort_t* whh1h = (ushort_t*)(base + whh1_off);
    ushort_t* whh2h = (ushort_t*)(base + whh2_off);
    f16_t*    wih1h = (f16_t*)(base + wih1_off);
    ushort_t* wih2h = (ushort_t*)(base + wih2_off);
    f16_t*    xb    = (f16_t*)(base + xb_off);
    float*    p1    = (float*)(base + p1_off);

    // poison sentinel comm buffers (data-as-signal)
    (void)hipMemsetAsync(comm1, 0xAA, (size_t)T_SEQ * H1 * 4, stream);
    (void)hipMemsetAsync(comm2, 0xAA, (size_t)T_SEQ * H2 * 4, stream);

    // f32 -> f16 conversions
    cvt_f16_kernel<<<2048, 256, 0, stream>>>(x_f,    xb,            T_SEQ * IN_SZ);
    cvt_f16_kernel<<<2048, 256, 0, stream>>>(wih1_f, wih1h,         G1 * IN_SZ);
    cvt_f16_kernel<<<2048, 256, 0, stream>>>(whh1_f, (f16_t*)whh1h, G1 * H1);
    cvt_f16_kernel<<<2048, 256, 0, stream>>>(wih2_f, (f16_t*)wih2h, G2 * H1);
    cvt_f16_kernel<<<4096, 256, 0, stream>>>(whh2_f, (f16_t*)whh2h, G2 * H2);

    // pre1 = x @ wih1^T + (bih1 + bhh1)   [f16 out]
    {
        dim3 grid(G1 / 64, T_SEQ / 64);
        gemm_bt_kernel<<<grid, 256, 0, stream>>>(xb, wih1h, pre1, bih1, bhh1,
                                                 T_SEQ, G1, IN_SZ);
    }

    // fused 2-layer recurrence: 256 blocks, ~136KB dynamic LDS
    {
        size_t shmem = (size_t)(16 * 512 + 32 * 512 + 8 * 1024 + 2 * 1024) * 4 + 2 * 32 * 4;
        fused_lstm_kernel<<<256, 256, shmem, stream>>>(
            pre1, whh1h, wih2h, whh2h, bih2, bhh2, comm1, comm2, T_SEQ);
    }

    // p1 = wl1 . h2[T-1] + bl1 ; out = wl2 . p1 + bl2
    const float* h2_last = (const float*)(comm2 + (size_t)(T_SEQ - 1) * H2);
    linear_vec_kernel<<<L1OUT / 4, 256, 0, stream>>>(wl1, bl1, h2_last, p1, L1OUT, H2);
    linear_vec_kernel<<<OUT_SZ / 4, 256, 0, stream>>>(wl2, bl2, p1, (float*)d_out, OUT_SZ, L1OUT);

    (void)in_sizes; (void)n_in; (void)out_size; (void)ws_size;
}

// Round 8
// 14645.364 us; speedup vs baseline: 2.0516x; 2.0516x over previous
//
#include <hip/hip_runtime.h>
#include <stdint.h>

typedef unsigned short ushort_t;
typedef _Float16 f16_t;
typedef __attribute__((ext_vector_type(2))) _Float16 half2;
typedef __attribute__((ext_vector_type(8))) _Float16 half8;
typedef __attribute__((ext_vector_type(4))) float f32x4;

#define T_SEQ 4096
#define IN_SZ 512
#define H1 1024
#define H2 2048
#define G1 (4*H1)   // 4096
#define G2 (4*H2)   // 8192
#define OUT_SZ 512
#define L1OUT 1024

#define SENT 0xAAAAAAAAu

__device__ __forceinline__ float f16_val(ushort_t v) {
    union { ushort_t u; _Float16 h; } x; x.u = v; return (float)x.h;
}
__device__ __forceinline__ half2 u2h(uint32_t w) {
    union { uint32_t u; half2 h; } x; x.u = w; return x.h;
}
__device__ __forceinline__ uint32_t pack_f16(float a, float b) {
    auto h = __builtin_amdgcn_cvt_pkrtz(a, b);   // __fp16 ext_vector(2) on gfx950
    union { decltype(h) h; uint32_t u; } x; x.h = h; return x.u;
}
// fast gate math
__device__ __forceinline__ float fsig(float x) {
    return __builtin_amdgcn_rcpf(1.0f + __expf(-x));
}
__device__ __forceinline__ float ftanh(float x) {
    return 1.0f - 2.0f * __builtin_amdgcn_rcpf(__expf(2.0f * x) + 1.0f);
}

// 2 MACs: acc += w·h for one packed f16 pair
__device__ __forceinline__ void dot2(float& acc, uint32_t w, uint32_t h) {
#if defined(__has_builtin) && __has_builtin(__builtin_amdgcn_fdot2)
    acc = __builtin_amdgcn_fdot2(u2h(w), u2h(h), acc, false);
#else
    half2 a = u2h(w), b = u2h(h);
    acc = fmaf((float)a.x, (float)b.x, acc);
    acc = fmaf((float)a.y, (float)b.y, acc);
#endif
}
#define DOT4(ACC, W, Hv) do { dot2(ACC, (W).x, (Hv).x); dot2(ACC, (W).y, (Hv).y); \
                              dot2(ACC, (W).z, (Hv).z); dot2(ACC, (W).w, (Hv).w); } while (0)

__device__ __forceinline__ uint64_t ald64(const uint64_t* p) {
    return __hip_atomic_load(p, __ATOMIC_RELAXED, __HIP_MEMORY_SCOPE_AGENT);
}
__device__ __forceinline__ int bad64(uint64_t q) {
    return (int)(((uint32_t)q == SENT) | ((uint32_t)(q >> 32) == SENT));
}

// ---------------- f32 -> f16 conversion ----------------
__global__ __launch_bounds__(256) void cvt_f16_kernel(const float* __restrict__ in,
                                                      f16_t* __restrict__ out, int n) {
    int i = blockIdx.x * 256 + threadIdx.x;
    int stride = gridDim.x * 256;
    for (; i < n; i += stride) out[i] = (f16_t)in[i];
}

// ---------------- f16 MFMA GEMM: C[M,N] = A[M,K] * B[N,K]^T + bias_a + bias_b, f16 out ----------
__global__ __launch_bounds__(256) void gemm_bt_kernel(const f16_t* __restrict__ A,
                                                      const f16_t* __restrict__ B,
                                                      f16_t* __restrict__ Cb,
                                                      const float* __restrict__ bias_a,
                                                      const float* __restrict__ bias_b,
                                                      int M, int N, int K) {
    int tid  = threadIdx.x;
    int wave = tid >> 6;
    int lane = tid & 63;
    int l15  = lane & 15;
    int quad = lane >> 4;
    int m0 = blockIdx.y * 64 + wave * 16;
    int n0 = blockIdx.x * 64;

    const f16_t* pa = A + (size_t)(m0 + l15) * K + quad * 8;
    f32x4 acc[4];
    #pragma unroll
    for (int i = 0; i < 4; ++i) acc[i] = (f32x4){0.f, 0.f, 0.f, 0.f};

    for (int kc = 0; kc < K; kc += 32) {
        half8 a = *(const half8*)(pa + kc);
        #pragma unroll
        for (int nf = 0; nf < 4; ++nf) {
            const f16_t* pb = B + (size_t)(n0 + nf * 16 + l15) * K + quad * 8 + kc;
            half8 b = *(const half8*)pb;
            acc[nf] = __builtin_amdgcn_mfma_f32_16x16x32_f16(a, b, acc[nf], 0, 0, 0);
        }
    }

    int rbase = quad * 4;
    #pragma unroll
    for (int nf = 0; nf < 4; ++nf) {
        int n = n0 + nf * 16 + l15;
        float bb = bias_a[n] + bias_b[n];
        #pragma unroll
        for (int r = 0; r < 4; ++r) {
            int m = m0 + rbase + r;
            Cb[(size_t)m * N + n] = (f16_t)(acc[nf][r] + bb);
        }
    }
}

// ---------------- Fused 2-layer LSTM recurrence, split-phase pipeline ----------------
// Round-4 14.35ms structure (the proven champion) with ONE change: both comm polls
// become register PREFETCHES issued at the correct time (publish + >=1.2us), validated
// at the original poll sites. Removes the cold cross-fabric fetch (~0.35-0.5us each)
// from the serial path at point of use.
//   comm1[s]: published mid-iter s (phase B) -> ISSUE at end of iter s (slack ~1.5us)
//             -> VALIDATE at phase A of iter s+1 (no barrier between issue and use).
//   comm2[s-2]: published end of iter s-1 (phase C) -> ISSUE right after hA/hB read
//             of iter s (slack ~1.3us); B+pre2 compute covers the fetch
//             -> VALIDATE at B'.
// Validation checks prefetched regs first (no load, no sleep on common path);
// reloads only on sentinel. Atomic loads: no remat (R5 trap), not sunk across barrier.
// R2's regression was mistimed issue (comm2 at loop top = 0 slack -> always-miss).
// 256 blocks x 256 threads (1 block/CU). Block b owns h1 units [4b,4b+4), h2 units
// [8b,8b+8). Phases: A(validate h1, stage) |barA| B(h1 dots+publish) pre2 B'(validate
// h2, stage) |barB| C(h2 dots+publish). comm f32, sentinel 0xAA, 64-bit polls.
__global__ __launch_bounds__(256, 1) void fused_lstm_kernel(
        const f16_t* __restrict__ pre1,       // f16 [T, 4096]
        const ushort_t* __restrict__ whh1h,   // f16 bits [4096, 1024]
        const ushort_t* __restrict__ wih2h,   // f16 bits [8192, 1024]
        const ushort_t* __restrict__ whh2h,   // f16 bits [8192, 2048]
        const float* __restrict__ bih2,
        const float* __restrict__ bhh2,
        uint32_t* __restrict__ comm1,         // f32 bits [T, 1024], pre-poisoned 0xAA
        uint32_t* __restrict__ comm2,         // f32 bits [T, 2048], pre-poisoned 0xAA
        int T) {
    extern __shared__ char smem[];
    uint32_t* whh1_w = (uint32_t*)smem;             // [16][512]  f16-pair words (32KB)
    uint32_t* wih2_w = whh1_w + 16 * 512;           // [32][512]  (64KB)
    uint32_t* whh2_w = wih2_w + 32 * 512;           // [8][1024]  gate0 (32KB)
    uint32_t* h1b    = whh2_w + 8 * 1024;           // [2][512]   packed h1 (4KB)
    uint32_t* h2b    = h1b + 2 * 512;               // [2][1024]  packed h2 (8KB)

    int tid = threadIdx.x;
    int blk = blockIdx.x;
    int u1  = tid >> 6;          // h1 unit (0..3), 64 lanes
    int ln1 = tid & 63;
    int u2l = tid >> 5;          // h2 unit (0..7), 32 lanes
    int ln2 = tid & 31;
    int wv  = tid >> 6;          // wave id

    // ---- stage resident weights into LDS (f16 bytes, same layout as the global rows) ----
    #pragma unroll
    for (int i = 0; i < 8; ++i) {            // whh1: 16 rows x 128 uint4
        int idx = tid + i * 256, r = idx >> 7, ch = idx & 127;
        size_t R = (size_t)(r & 3) * H1 + blk * 4 + (r >> 2);
        *(uint4*)&whh1_w[r * 512 + ch * 4] = *(const uint4*)(whh1h + R * H1 + ch * 8);
    }
    #pragma unroll
    for (int i = 0; i < 16; ++i) {           // wih2: 32 rows x 128 uint4
        int idx = tid + i * 256, r = idx >> 7, ch = idx & 127;
        size_t R = (size_t)(r & 3) * H2 + blk * 8 + (r >> 2);
        *(uint4*)&wih2_w[r * 512 + ch * 4] = *(const uint4*)(wih2h + R * H1 + ch * 8);
    }
    #pragma unroll
    for (int i = 0; i < 8; ++i) {            // whh2 gate0: 8 rows x 256 uint4
        int idx = tid + i * 256, r = idx >> 8, ch = idx & 255;
        size_t R = (size_t)(blk * 8 + r);
        *(uint4*)&whh2_w[r * 1024 + ch * 4] = *(const uint4*)(whh2h + R * H2 + ch * 8);
    }

    // whh2 gates 1..3 (compiler schedules these at point of use in C; R4-verified ~free)
    uint4 wreg[24];
    #pragma unroll
    for (int g = 1; g < 4; ++g) {
        size_t R = (size_t)g * H2 + blk * 8 + u2l;
        #pragma unroll
        for (int j = 0; j < 8; ++j)
            wreg[(g - 1) * 8 + j] = *(const uint4*)(whh2h + R * H2 + ln2 * 8 + j * 256);
    }

    float b2g[4];
    {
        int U = blk * 8 + u2l;
        #pragma unroll
        for (int g = 0; g < 4; ++g) b2g[g] = bih2[g * H2 + U] + bhh2[g * H2 + U];
    }

    float pc[4] = {0.f, 0.f, 0.f, 0.f};
    if (ln1 == 0) {
        #pragma unroll
        for (int g = 0; g < 4; ++g)
            pc[g] = f16_val(((const ushort_t*)pre1)[(size_t)0 * G1 + g * H1 + blk * 4 + u1]);
    }

    float c1 = 0.0f;   // ln1==0
    float c2 = 0.0f;   // ln2==0

    // prefetched comm1 row (for next iteration's phase A); init forces reload at s=1
    uint64_t c1q0 = 0xAAAAAAAAAAAAAAAAull, c1q1 = 0xAAAAAAAAAAAAAAAAull;

    for (int s = 0; s <= T; ++s) {
        // ---- prefetch pre1[s+1] ----
        float pn[4] = {0.f, 0.f, 0.f, 0.f};
        if (ln1 == 0) {
            int row = (s + 1 < T) ? s + 1 : T - 1;
            #pragma unroll
            for (int g = 0; g < 4; ++g)
                pn[g] = f16_val(((const ushort_t*)pre1)[(size_t)row * G1 + g * H1 + blk * 4 + u1]);
        }

        // ---- Phase A: validate prefetched comm1[s-1]; reload only on sentinel ----
        if (s >= 1) {
            const uint64_t* s1 = (const uint64_t*)(comm1 + (size_t)(s - 1) * H1);
            uint64_t q0 = c1q0, q1 = c1q1;
            while (bad64(q0) | bad64(q1)) {
                q0 = ald64(&s1[tid]);
                q1 = ald64(&s1[tid + 256]);
                if (!(bad64(q0) | bad64(q1))) break;
                __builtin_amdgcn_s_sleep(1);
            }
            uint32_t* d = h1b + ((s - 1) & 1) * 512;
            union { uint64_t q; float f[2]; } x;
            x.q = q0; d[tid]       = pack_f16(x.f[0], x.f[1]);
            x.q = q1; d[tid + 256] = pack_f16(x.f[0], x.f[1]);
        }
        __syncthreads();   // barrier A

        const uint32_t* h1p = h1b + ((s - 1) & 1) * 512;
        uint4 hA, hB;
        if (s >= 1) {
            hA = *(const uint4*)&h1p[ln1 * 4];
            hB = *(const uint4*)&h1p[ln1 * 4 + 256];
        }

        // ---- issue comm2[s-2] prefetch loads NOW (published end of iter s-1;
        //      slack ~1.3us; B+pre2 compute below covers the fetch) ----
        const uint64_t* s2 = (const uint64_t*)(comm2 + (size_t)((s >= 2) ? s - 2 : 0) * H2);
        uint64_t q2[4];
        if (s >= 2) {
            #pragma unroll
            for (int k = 0; k < 4; ++k) q2[k] = ald64(&s2[tid + k * 256]);
        }

        // ---- Phase B: h1[s] ----
        if (s < T) {
            float a0 = 0.f, a1 = 0.f, a2 = 0.f, a3 = 0.f;
            if (s >= 1) {
                uint4 w;
                w = *(const uint4*)&whh1_w[(u1 * 4 + 0) * 512 + ln1 * 4];       DOT4(a0, w, hA);
                w = *(const uint4*)&whh1_w[(u1 * 4 + 0) * 512 + ln1 * 4 + 256]; DOT4(a0, w, hB);
                w = *(const uint4*)&whh1_w[(u1 * 4 + 1) * 512 + ln1 * 4];       DOT4(a1, w, hA);
                w = *(const uint4*)&whh1_w[(u1 * 4 + 1) * 512 + ln1 * 4 + 256]; DOT4(a1, w, hB);
                w = *(const uint4*)&whh1_w[(u1 * 4 + 2) * 512 + ln1 * 4];       DOT4(a2, w, hA);
                w = *(const uint4*)&whh1_w[(u1 * 4 + 2) * 512 + ln1 * 4 + 256]; DOT4(a2, w, hB);
                w = *(const uint4*)&whh1_w[(u1 * 4 + 3) * 512 + ln1 * 4];       DOT4(a3, w, hA);
                w = *(const uint4*)&whh1_w[(u1 * 4 + 3) * 512 + ln1 * 4 + 256]; DOT4(a3, w, hB);
            }
            #pragma unroll
            for (int off = 32; off > 0; off >>= 1) {
                a0 += __shfl_down(a0, off, 64); a1 += __shfl_down(a1, off, 64);
                a2 += __shfl_down(a2, off, 64); a3 += __shfl_down(a3, off, 64);
            }
            if (ln1 == 0) {
                float iv = fsig(pc[0] + a0);
                float fv = fsig(pc[1] + a1);
                float gv = ftanh(pc[2] + a2);
                float ov = fsig(pc[3] + a3);
                c1 = fv * c1 + iv * gv;
                float h = ov * ftanh(c1);
                union { float f; uint32_t u; } x; x.f = h;
                __hip_atomic_store(&comm1[(size_t)s * H1 + blk * 4 + u1], x.u,
                                   __ATOMIC_RELAXED, __HIP_MEMORY_SCOPE_AGENT);
            }
        }

        // ---- pre2[s-1] = this block's 32 wih2 rows · h1[s-1] ----
        float pb[8];
        if (s >= 1) {
            float pv[8];
            #pragma unroll
            for (int d = 0; d < 8; ++d) pv[d] = 0.f;
            #pragma unroll
            for (int d = 0; d < 8; ++d) {
                int r = wv * 8 + d;
                uint4 w0 = *(const uint4*)&wih2_w[r * 512 + ln1 * 4];
                uint4 w1 = *(const uint4*)&wih2_w[r * 512 + ln1 * 4 + 256];
                DOT4(pv[d], w0, hA);
                DOT4(pv[d], w1, hB);
            }
            #pragma unroll
            for (int off = 32; off > 0; off >>= 1) {
                #pragma unroll
                for (int d = 0; d < 8; ++d) pv[d] += __shfl_down(pv[d], off, 64);
            }
            #pragma unroll
            for (int d = 0; d < 8; ++d) pb[d] = __shfl(pv[d], 0, 64);
        }

        // ---- Phase B': validate prefetched comm2[s-2]; reload only on sentinel ----
        if (s >= 2) {
            for (;;) {
                int bad = 0;
                #pragma unroll
                for (int k = 0; k < 4; ++k) bad |= bad64(q2[k]);
                if (!bad) break;
                #pragma unroll
                for (int k = 0; k < 4; ++k) q2[k] = ald64(&s2[tid + k * 256]);
                int bad2 = 0;
                #pragma unroll
                for (int k = 0; k < 4; ++k) bad2 |= bad64(q2[k]);
                if (!bad2) break;
                __builtin_amdgcn_s_sleep(1);
            }
            uint32_t* d = h2b + (s & 1) * 1024;
            #pragma unroll
            for (int k = 0; k < 4; ++k) {
                union { uint64_t q; float f[2]; } x; x.q = q2[k];
                d[tid + k * 256] = pack_f16(x.f[0], x.f[1]);
            }
        }
        __syncthreads();   // barrier B

        // ---- Phase C: h2[s-1] ----
        if (s >= 1) {
            float b0 = 0.f, b1 = 0.f, b2 = 0.f, b3 = 0.f;
            if (s >= 2) {
                const uint32_t* h2p = h2b + (s & 1) * 1024;
                #pragma unroll
                for (int j = 0; j < 8; ++j) {
                    uint4 hx = *(const uint4*)&h2p[ln2 * 4 + j * 128];
                    uint4 w0 = *(const uint4*)&whh2_w[u2l * 1024 + ln2 * 4 + j * 128];
                    DOT4(b0, w0, hx);
                    DOT4(b1, wreg[j], hx);
                    DOT4(b2, wreg[8 + j], hx);
                    DOT4(b3, wreg[16 + j], hx);
                }
            }
            #pragma unroll
            for (int off = 16; off > 0; off >>= 1) {
                b0 += __shfl_down(b0, off, 32); b1 += __shfl_down(b1, off, 32);
                b2 += __shfl_down(b2, off, 32); b3 += __shfl_down(b3, off, 32);
            }
            if (ln2 == 0) {
                int half = u2l & 1;
                float iv = fsig(pb[half * 4 + 0] + b2g[0] + b0);
                float fv = fsig(pb[half * 4 + 1] + b2g[1] + b1);
                float gv = ftanh(pb[half * 4 + 2] + b2g[2] + b2);
                float ov = fsig(pb[half * 4 + 3] + b2g[3] + b3);
                c2 = fv * c2 + iv * gv;
                float h = ov * ftanh(c2);
                union { float f; uint32_t u; } x; x.f = h;
                __hip_atomic_store(&comm2[(size_t)(s - 1) * H2 + blk * 8 + u2l], x.u,
                                   __ATOMIC_RELAXED, __HIP_MEMORY_SCOPE_AGENT);
            }
        }

        // ---- issue comm1[s] prefetch for next iteration's phase A
        //      (published in phase B above, ~1.5us ago -> visible by now) ----
        if (s < T) {
            const uint64_t* s1n = (const uint64_t*)(comm1 + (size_t)s * H1);
            c1q0 = ald64(&s1n[tid]);
            c1q1 = ald64(&s1n[tid + 256]);
        }

        #pragma unroll
        for (int g = 0; g < 4; ++g) pc[g] = pn[g];
    }
}

// ---------------- small matvec ----------------
__global__ __launch_bounds__(256) void linear_vec_kernel(const float* __restrict__ W,
                                                         const float* __restrict__ bias,
                                                         const float* __restrict__ x,
                                                         float* __restrict__ out,
                                                         int N, int K) {
    int wave = threadIdx.x >> 6;
    int lane = threadIdx.x & 63;
    int j = blockIdx.x * 4 + wave;
    if (j >= N) return;
    const float* wr = W + (size_t)j * K;
    float s = 0.0f;
    for (int k = lane; k < K; k += 64) s += wr[k] * x[k];
    #pragma unroll
    for (int off = 32; off > 0; off >>= 1) s += __shfl_down(s, off, 64);
    if (lane == 0) out[j] = s + bias[j];
}

extern "C" void kernel_launch(void* const* d_in, const int* in_sizes, int n_in,
                              void* d_out, int out_size, void* d_ws, size_t ws_size,
                              hipStream_t stream) {
    const float* x_f    = (const float*)d_in[0];
    const float* wih1_f = (const float*)d_in[1];
    const float* whh1_f = (const float*)d_in[2];
    const float* bih1   = (const float*)d_in[3];
    const float* bhh1   = (const float*)d_in[4];
    const float* wih2_f = (const float*)d_in[5];
    const float* whh2_f = (const float*)d_in[6];
    const float* bih2   = (const float*)d_in[7];
    const float* bhh2   = (const float*)d_in[8];
    const float* wl1    = (const float*)d_in[9];
    const float* bl1    = (const float*)d_in[10];
    const float* wl2    = (const float*)d_in[11];
    const float* bl2    = (const float*)d_in[12];

    uint8_t* base = (uint8_t*)d_ws;
    size_t off = 0;
    auto alloc = [&](size_t bytes) { size_t o = off; off = (off + bytes + 255) & ~(size_t)255; return o; };

    size_t pre1_off  = alloc((size_t)T_SEQ * G1 * 2);   // f16 [T,4096]
    size_t comm1_off = alloc((size_t)T_SEQ * H1 * 4);   // f32 [T,1024]
    size_t comm2_off = alloc((size_t)T_SEQ * H2 * 4);   // f32 [T,2048]
    size_t whh1_off  = alloc((size_t)G1 * H1 * 2);
    size_t whh2_off  = alloc((size_t)G2 * H2 * 2);
    size_t wih1_off  = alloc((size_t)G1 * IN_SZ * 2);
    size_t wih2_off  = alloc((size_t)G2 * H1 * 2);
    size_t xb_off    = alloc((size_t)T_SEQ * IN_SZ * 2);
    size_t p1_off    = alloc((size_t)L1OUT * 4);

    f16_t*    pre1  = (f16_t*)(base + pre1_off);
    uint32_t* comm1 = (uint32_t*)(base + comm1_off);
    uint32_t* comm2 = (uint32_t*)(base + comm2_off);
    ushort_t* whh1h = (ushort_t*)(base + whh1_off);
    ushort_t* whh2h = (ushort_t*)(base + whh2_off);
    f16_t*    wih1h = (f16_t*)(base + wih1_off);
    ushort_t* wih2h = (ushort_t*)(base + wih2_off);
    f16_t*    xb    = (f16_t*)(base + xb_off);
    float*    p1    = (float*)(base + p1_off);

    // poison sentinel comm buffers (data-as-signal)
    (void)hipMemsetAsync(comm1, 0xAA, (size_t)T_SEQ * H1 * 4, stream);
    (void)hipMemsetAsync(comm2, 0xAA, (size_t)T_SEQ * H2 * 4, stream);

    // f32 -> f16 conversions
    cvt_f16_kernel<<<2048, 256, 0, stream>>>(x_f,    xb,            T_SEQ * IN_SZ);
    cvt_f16_kernel<<<2048, 256, 0, stream>>>(wih1_f, wih1h,         G1 * IN_SZ);
    cvt_f16_kernel<<<2048, 256, 0, stream>>>(whh1_f, (f16_t*)whh1h, G1 * H1);
    cvt_f16_kernel<<<2048, 256, 0, stream>>>(wih2_f, (f16_t*)wih2h, G2 * H1);
    cvt_f16_kernel<<<4096, 256, 0, stream>>>(whh2_f, (f16_t*)whh2h, G2 * H2);

    // pre1 = x @ wih1^T + (bih1 + bhh1)   [f16 out]
    {
        dim3 grid(G1 / 64, T_SEQ / 64);
        gemm_bt_kernel<<<grid, 256, 0, stream>>>(xb, wih1h, pre1, bih1, bhh1,
                                                 T_SEQ, G1, IN_SZ);
    }

    // fused 2-layer recurrence: 256 blocks, 140KB dynamic LDS
    {
        size_t shmem = (size_t)(16 * 512 + 32 * 512 + 8 * 1024 + 2 * 512 + 2 * 1024) * 4;
        fused_lstm_kernel<<<256, 256, shmem, stream>>>(
            pre1, whh1h, wih2h, whh2h, bih2, bhh2, comm1, comm2, T_SEQ);
    }

    // p1 = wl1 . h2[T-1] + bl1 ; out = wl2 . p1 + bl2
    const float* h2_last = (const float*)(comm2 + (size_t)(T_SEQ - 1) * H2);
    linear_vec_kernel<<<L1OUT / 4, 256, 0, stream>>>(wl1, bl1, h2_last, p1, L1OUT, H2);
    linear_vec_kernel<<<OUT_SZ / 4, 256, 0, stream>>>(wl2, bl2, p1, (float*)d_out, OUT_SZ, L1OUT);

    (void)in_sizes; (void)n_in; (void)out_size; (void)ws_size;
}

// Round 10
// 11347.352 us; speedup vs baseline: 2.6479x; 1.2906x over previous
//
#include <hip/hip_runtime.h>
#include <stdint.h>

typedef unsigned short ushort_t;
typedef _Float16 f16_t;
typedef __attribute__((ext_vector_type(2))) _Float16 half2;
typedef __attribute__((ext_vector_type(8))) _Float16 half8;
typedef __attribute__((ext_vector_type(4))) float f32x4;

#define T_SEQ 4096
#define IN_SZ 512
#define H1 1024
#define H2 2048
#define G1 (4*H1)   // 4096
#define G2 (4*H2)   // 8192
#define OUT_SZ 512
#define L1OUT 1024

#define SENT 0xAAAAAAAAu

__device__ __forceinline__ float f16_val(ushort_t v) {
    union { ushort_t u; _Float16 h; } x; x.u = v; return (float)x.h;
}
__device__ __forceinline__ half2 u2h(uint32_t w) {
    union { uint32_t u; half2 h; } x; x.u = w; return x.h;
}
__device__ __forceinline__ uint32_t pack_f16(float a, float b) {
    auto h = __builtin_amdgcn_cvt_pkrtz(a, b);   // __fp16 ext_vector(2) on gfx950
    union { decltype(h) h; uint32_t u; } x; x.h = h; return x.u;
}
// fast gate math
__device__ __forceinline__ float fsig(float x) {
    return __builtin_amdgcn_rcpf(1.0f + __expf(-x));
}
__device__ __forceinline__ float ftanh(float x) {
    return 1.0f - 2.0f * __builtin_amdgcn_rcpf(__expf(2.0f * x) + 1.0f);
}

// 2 MACs: acc += w·h for one packed f16 pair
__device__ __forceinline__ void dot2(float& acc, uint32_t w, uint32_t h) {
#if defined(__has_builtin) && __has_builtin(__builtin_amdgcn_fdot2)
    acc = __builtin_amdgcn_fdot2(u2h(w), u2h(h), acc, false);
#else
    half2 a = u2h(w), b = u2h(h);
    acc = fmaf((float)a.x, (float)b.x, acc);
    acc = fmaf((float)a.y, (float)b.y, acc);
#endif
}
#define DOT4(ACC, W, Hv) do { dot2(ACC, (W).x, (Hv).x); dot2(ACC, (W).y, (Hv).y); \
                              dot2(ACC, (W).z, (Hv).z); dot2(ACC, (W).w, (Hv).w); } while (0)

// ---------------- DPP reductions (VALU pipe, ~4-8cy/round vs ds_bpermute ~80cy) ----
// row_shr:N = 0x110|N ; row_bcast15 = 0x142 ; row_bcast31 = 0x143 (gfx9 DPP ctrls)
// ctrl must be a compile-time constant -> template parameter (R9 compile-fix).
template<int CTRL>
__device__ __forceinline__ float dpp_add(float x) {
    union { float f; int i; } s, t;
    s.f = x;
    t.i = __builtin_amdgcn_update_dpp(0, s.i, CTRL, 0xF, 0xF, true);
    return x + t.f;
}
// sum of all 64 lanes -> valid on lane 63
__device__ __forceinline__ float red64(float x) {
    x = dpp_add<0x111>(x);   // row_shr:1
    x = dpp_add<0x112>(x);   // row_shr:2
    x = dpp_add<0x114>(x);   // row_shr:4
    x = dpp_add<0x118>(x);   // row_shr:8  -> lane15 of each row = row sum
    x = dpp_add<0x142>(x);   // row_bcast15 -> lane31 = rows0+1, lane63 = rows2+3
    x = dpp_add<0x143>(x);   // row_bcast31 -> lane63 = total
    return x;
}
// sum of each 32-lane half -> valid on lane 31 (lower) and lane 63 (upper)
__device__ __forceinline__ float red32(float x) {
    x = dpp_add<0x111>(x);
    x = dpp_add<0x112>(x);
    x = dpp_add<0x114>(x);
    x = dpp_add<0x118>(x);
    x = dpp_add<0x142>(x);   // lane31 = lanes0-31 sum; lane63 = lanes32-63 sum
    return x;
}
__device__ __forceinline__ float bcast_lane63(float x) {
    union { float f; int i; } s;
    s.f = x;
    s.i = __builtin_amdgcn_readlane(s.i, 63);
    return s.f;
}

// ---------------- f32 -> f16 conversion ----------------
__global__ __launch_bounds__(256) void cvt_f16_kernel(const float* __restrict__ in,
                                                      f16_t* __restrict__ out, int n) {
    int i = blockIdx.x * 256 + threadIdx.x;
    int stride = gridDim.x * 256;
    for (; i < n; i += stride) out[i] = (f16_t)in[i];
}

// ---------------- f16 MFMA GEMM: C[M,N] = A[M,K] * B[N,K]^T + bias_a + bias_b, f16 out ----------
__global__ __launch_bounds__(256) void gemm_bt_kernel(const f16_t* __restrict__ A,
                                                      const f16_t* __restrict__ B,
                                                      f16_t* __restrict__ Cb,
                                                      const float* __restrict__ bias_a,
                                                      const float* __restrict__ bias_b,
                                                      int M, int N, int K) {
    int tid  = threadIdx.x;
    int wave = tid >> 6;
    int lane = tid & 63;
    int l15  = lane & 15;
    int quad = lane >> 4;
    int m0 = blockIdx.y * 64 + wave * 16;
    int n0 = blockIdx.x * 64;

    const f16_t* pa = A + (size_t)(m0 + l15) * K + quad * 8;
    f32x4 acc[4];
    #pragma unroll
    for (int i = 0; i < 4; ++i) acc[i] = (f32x4){0.f, 0.f, 0.f, 0.f};

    for (int kc = 0; kc < K; kc += 32) {
        half8 a = *(const half8*)(pa + kc);
        #pragma unroll
        for (int nf = 0; nf < 4; ++nf) {
            const f16_t* pb = B + (size_t)(n0 + nf * 16 + l15) * K + quad * 8 + kc;
            half8 b = *(const half8*)pb;
            acc[nf] = __builtin_amdgcn_mfma_f32_16x16x32_f16(a, b, acc[nf], 0, 0, 0);
        }
    }

    int rbase = quad * 4;
    #pragma unroll
    for (int nf = 0; nf < 4; ++nf) {
        int n = n0 + nf * 16 + l15;
        float bb = bias_a[n] + bias_b[n];
        #pragma unroll
        for (int r = 0; r < 4; ++r) {
            int m = m0 + rbase + r;
            Cb[(size_t)m * N + n] = (f16_t)(acc[nf][r] + bb);
        }
    }
}

// ---------------- Fused 2-layer LSTM recurrence, split-phase pipeline ----------------
// Round-4 14.35ms champion structure with ONE change: the three cross-lane reduce
// ladders (phase B 4x wave64, pre2 8x wave64, phase C 4x per-32) switch from
// __shfl_down (ds_bpermute, ~80cy/dependent round on the DS pipe, 17 rounds/step
// fully exposed at 1 wave/SIMD) to DPP v_add reductions (VALU pipe, ~4-8cy/round).
// Totals land on lane 63 (wave64) / lanes 31 & 63 (per-32), so the gate lanes move:
// phase B gates+publish on ln1==63 (was 0), phase C on ln2==31 (was 0). pre2
// broadcasts via readlane(.,63). R8's poll prefetch is REVERTED (proven null).
// 256 blocks x 256 threads (1 block/CU, persistent). Block b owns h1 units [4b,4b+4),
// h2 units [8b,8b+8). Iteration s:
//   A: poll h1[s-1] (published mid prev iter -> slack), stage packed-f16, barrier A
//   B: h1[s] = gates(whh1·h1[s-1] + pre1[s]), publish f32; pre2[s-1] = wih2-slice·h1[s-1]
//   B': poll h2[s-2] (published END of prev iter; slack = A+B phases), stage, barrier B
//   C: h2[s-1] = gates(whh2·h2[s-2] + pre2[s-1]), publish f32
// whh2 gate0 in LDS, gates 1..3 loaded pre-loop (compiler schedules the re-fetch at
// point of use in C; R4-verified ~free). comm f32, sentinel 0xAA, 64-bit polls.
__global__ __launch_bounds__(256, 1) void fused_lstm_kernel(
        const f16_t* __restrict__ pre1,       // f16 [T, 4096]
        const ushort_t* __restrict__ whh1h,   // f16 bits [4096, 1024]
        const ushort_t* __restrict__ wih2h,   // f16 bits [8192, 1024]
        const ushort_t* __restrict__ whh2h,   // f16 bits [8192, 2048]
        const float* __restrict__ bih2,
        const float* __restrict__ bhh2,
        uint32_t* __restrict__ comm1,         // f32 bits [T, 1024], pre-poisoned 0xAA
        uint32_t* __restrict__ comm2,         // f32 bits [T, 2048], pre-poisoned 0xAA
        int T) {
    extern __shared__ char smem[];
    uint32_t* whh1_w = (uint32_t*)smem;             // [16][512]  f16-pair words (32KB)
    uint32_t* wih2_w = whh1_w + 16 * 512;           // [32][512]  (64KB)
    uint32_t* whh2_w = wih2_w + 32 * 512;           // [8][1024]  gate0 (32KB)
    uint32_t* h1b    = whh2_w + 8 * 1024;           // [2][512]   packed h1 (4KB)
    uint32_t* h2b    = h1b + 2 * 512;               // [2][1024]  packed h2 (8KB)

    int tid = threadIdx.x;
    int blk = blockIdx.x;
    int u1  = tid >> 6;          // h1 unit (0..3), 64 lanes
    int ln1 = tid & 63;
    int u2l = tid >> 5;          // h2 unit (0..7), 32 lanes
    int ln2 = tid & 31;
    int wv  = tid >> 6;          // wave id

    // ---- stage resident weights into LDS (f16 bytes, same layout as the global rows) ----
    #pragma unroll
    for (int i = 0; i < 8; ++i) {            // whh1: 16 rows x 128 uint4
        int idx = tid + i * 256, r = idx >> 7, ch = idx & 127;
        size_t R = (size_t)(r & 3) * H1 + blk * 4 + (r >> 2);
        *(uint4*)&whh1_w[r * 512 + ch * 4] = *(const uint4*)(whh1h + R * H1 + ch * 8);
    }
    #pragma unroll
    for (int i = 0; i < 16; ++i) {           // wih2: 32 rows x 128 uint4
        int idx = tid + i * 256, r = idx >> 7, ch = idx & 127;
        size_t R = (size_t)(r & 3) * H2 + blk * 8 + (r >> 2);
        *(uint4*)&wih2_w[r * 512 + ch * 4] = *(const uint4*)(wih2h + R * H1 + ch * 8);
    }
    #pragma unroll
    for (int i = 0; i < 8; ++i) {            // whh2 gate0: 8 rows x 256 uint4
        int idx = tid + i * 256, r = idx >> 8, ch = idx & 255;
        size_t R = (size_t)(blk * 8 + r);
        *(uint4*)&whh2_w[r * 1024 + ch * 4] = *(const uint4*)(whh2h + R * H2 + ch * 8);
    }

    // whh2 gates 1..3 (compiler schedules these at point of use in C; R4-verified ~free)
    uint4 wreg[24];
    #pragma unroll
    for (int g = 1; g < 4; ++g) {
        size_t R = (size_t)g * H2 + blk * 8 + u2l;
        #pragma unroll
        for (int j = 0; j < 8; ++j)
            wreg[(g - 1) * 8 + j] = *(const uint4*)(whh2h + R * H2 + ln2 * 8 + j * 256);
    }

    float b2g[4];
    {
        int U = blk * 8 + u2l;
        #pragma unroll
        for (int g = 0; g < 4; ++g) b2g[g] = bih2[g * H2 + U] + bhh2[g * H2 + U];
    }

    float pc[4] = {0.f, 0.f, 0.f, 0.f};
    if (ln1 == 63) {
        #pragma unroll
        for (int g = 0; g < 4; ++g)
            pc[g] = f16_val(((const ushort_t*)pre1)[(size_t)0 * G1 + g * H1 + blk * 4 + u1]);
    }

    float c1 = 0.0f;   // ln1==63
    float c2 = 0.0f;   // ln2==31

    for (int s = 0; s <= T; ++s) {
        // ---- prefetch pre1[s+1] ----
        float pn[4] = {0.f, 0.f, 0.f, 0.f};
        if (ln1 == 63) {
            int row = (s + 1 < T) ? s + 1 : T - 1;
            #pragma unroll
            for (int g = 0; g < 4; ++g)
                pn[g] = f16_val(((const ushort_t*)pre1)[(size_t)row * G1 + g * H1 + blk * 4 + u1]);
        }

        // ---- Phase A: poll h1[s-1] (64-bit loads), stage packed f16 ----
        if (s >= 1) {
            const uint64_t* s1 = (const uint64_t*)(comm1 + (size_t)(s - 1) * H1);
            uint64_t q0, q1;
            for (;;) {
                q0 = __hip_atomic_load(&s1[tid],       __ATOMIC_RELAXED, __HIP_MEMORY_SCOPE_AGENT);
                q1 = __hip_atomic_load(&s1[tid + 256], __ATOMIC_RELAXED, __HIP_MEMORY_SCOPE_AGENT);
                if ((uint32_t)q0 != SENT && (uint32_t)(q0 >> 32) != SENT &&
                    (uint32_t)q1 != SENT && (uint32_t)(q1 >> 32) != SENT) break;
                __builtin_amdgcn_s_sleep(1);
            }
            uint32_t* d = h1b + ((s - 1) & 1) * 512;
            union { uint64_t q; float f[2]; } x;
            x.q = q0; d[tid]       = pack_f16(x.f[0], x.f[1]);
            x.q = q1; d[tid + 256] = pack_f16(x.f[0], x.f[1]);
        }
        __syncthreads();   // barrier A

        const uint32_t* h1p = h1b + ((s - 1) & 1) * 512;
        uint4 hA, hB;
        if (s >= 1) {
            hA = *(const uint4*)&h1p[ln1 * 4];
            hB = *(const uint4*)&h1p[ln1 * 4 + 256];
        }

        // ---- Phase B: h1[s] ----
        if (s < T) {
            float a0 = 0.f, a1 = 0.f, a2 = 0.f, a3 = 0.f;
            if (s >= 1) {
                uint4 w;
                w = *(const uint4*)&whh1_w[(u1 * 4 + 0) * 512 + ln1 * 4];       DOT4(a0, w, hA);
                w = *(const uint4*)&whh1_w[(u1 * 4 + 0) * 512 + ln1 * 4 + 256]; DOT4(a0, w, hB);
                w = *(const uint4*)&whh1_w[(u1 * 4 + 1) * 512 + ln1 * 4];       DOT4(a1, w, hA);
                w = *(const uint4*)&whh1_w[(u1 * 4 + 1) * 512 + ln1 * 4 + 256]; DOT4(a1, w, hB);
                w = *(const uint4*)&whh1_w[(u1 * 4 + 2) * 512 + ln1 * 4];       DOT4(a2, w, hA);
                w = *(const uint4*)&whh1_w[(u1 * 4 + 2) * 512 + ln1 * 4 + 256]; DOT4(a2, w, hB);
                w = *(const uint4*)&whh1_w[(u1 * 4 + 3) * 512 + ln1 * 4];       DOT4(a3, w, hA);
                w = *(const uint4*)&whh1_w[(u1 * 4 + 3) * 512 + ln1 * 4 + 256]; DOT4(a3, w, hB);
            }
            a0 = red64(a0); a1 = red64(a1); a2 = red64(a2); a3 = red64(a3);
            if (ln1 == 63) {
                float iv = fsig(pc[0] + a0);
                float fv = fsig(pc[1] + a1);
                float gv = ftanh(pc[2] + a2);
                float ov = fsig(pc[3] + a3);
                c1 = fv * c1 + iv * gv;
                float h = ov * ftanh(c1);
                union { float f; uint32_t u; } x; x.f = h;
                __hip_atomic_store(&comm1[(size_t)s * H1 + blk * 4 + u1], x.u,
                                   __ATOMIC_RELAXED, __HIP_MEMORY_SCOPE_AGENT);
            }
        }

        // ---- pre2[s-1] = this block's 32 wih2 rows · h1[s-1] ----
        float pb[8];
        if (s >= 1) {
            float pv[8];
            #pragma unroll
            for (int d = 0; d < 8; ++d) pv[d] = 0.f;
            #pragma unroll
            for (int d = 0; d < 8; ++d) {
                int r = wv * 8 + d;
                uint4 w0 = *(const uint4*)&wih2_w[r * 512 + ln1 * 4];
                uint4 w1 = *(const uint4*)&wih2_w[r * 512 + ln1 * 4 + 256];
                DOT4(pv[d], w0, hA);
                DOT4(pv[d], w1, hB);
            }
            #pragma unroll
            for (int d = 0; d < 8; ++d) pb[d] = bcast_lane63(red64(pv[d]));
        }

        // ---- Phase B': poll h2[s-2], stage packed f16 ----
        if (s >= 2) {
            const uint64_t* s2 = (const uint64_t*)(comm2 + (size_t)(s - 2) * H2);
            uint64_t q[4];
            for (;;) {
                #pragma unroll
                for (int k = 0; k < 4; ++k)
                    q[k] = __hip_atomic_load(&s2[tid + k * 256], __ATOMIC_RELAXED,
                                             __HIP_MEMORY_SCOPE_AGENT);
                bool bad = false;
                #pragma unroll
                for (int k = 0; k < 4; ++k)
                    bad |= ((uint32_t)q[k] == SENT) | ((uint32_t)(q[k] >> 32) == SENT);
                if (!bad) break;
                __builtin_amdgcn_s_sleep(1);
            }
            uint32_t* d = h2b + (s & 1) * 1024;
            #pragma unroll
            for (int k = 0; k < 4; ++k) {
                union { uint64_t q; float f[2]; } x; x.q = q[k];
                d[tid + k * 256] = pack_f16(x.f[0], x.f[1]);
            }
        }
        __syncthreads();   // barrier B

        // ---- Phase C: h2[s-1] ----
        if (s >= 1) {
            float b0 = 0.f, b1 = 0.f, b2 = 0.f, b3 = 0.f;
            if (s >= 2) {
                const uint32_t* h2p = h2b + (s & 1) * 1024;
                #pragma unroll
                for (int j = 0; j < 8; ++j) {
                    uint4 hx = *(const uint4*)&h2p[ln2 * 4 + j * 128];
                    uint4 w0 = *(const uint4*)&whh2_w[u2l * 1024 + ln2 * 4 + j * 128];
                    DOT4(b0, w0, hx);
                    DOT4(b1, wreg[j], hx);
                    DOT4(b2, wreg[8 + j], hx);
                    DOT4(b3, wreg[16 + j], hx);
                }
            }
            b0 = red32(b0); b1 = red32(b1); b2 = red32(b2); b3 = red32(b3);
            if (ln2 == 31) {   // per-32 totals live on wave lanes 31 and 63
                int half = u2l & 1;
                float iv = fsig(pb[half * 4 + 0] + b2g[0] + b0);
                float fv = fsig(pb[half * 4 + 1] + b2g[1] + b1);
                float gv = ftanh(pb[half * 4 + 2] + b2g[2] + b2);
                float ov = fsig(pb[half * 4 + 3] + b2g[3] + b3);
                c2 = fv * c2 + iv * gv;
                float h = ov * ftanh(c2);
                union { float f; uint32_t u; } x; x.f = h;
                __hip_atomic_store(&comm2[(size_t)(s - 1) * H2 + blk * 8 + u2l], x.u,
                                   __ATOMIC_RELAXED, __HIP_MEMORY_SCOPE_AGENT);
            }
        }

        #pragma unroll
        for (int g = 0; g < 4; ++g) pc[g] = pn[g];
    }
}

// ---------------- small matvec ----------------
__global__ __launch_bounds__(256) void linear_vec_kernel(const float* __restrict__ W,
                                                         const float* __restrict__ bias,
                                                         const float* __restrict__ x,
                                                         float* __restrict__ out,
                                                         int N, int K) {
    int wave = threadIdx.x >> 6;
    int lane = threadIdx.x & 63;
    int j = blockIdx.x * 4 + wave;
    if (j >= N) return;
    const float* wr = W + (size_t)j * K;
    float s = 0.0f;
    for (int k = lane; k < K; k += 64) s += wr[k] * x[k];
    #pragma unroll
    for (int off = 32; off > 0; off >>= 1) s += __shfl_down(s, off, 64);
    if (lane == 0) out[j] = s + bias[j];
}

extern "C" void kernel_launch(void* const* d_in, const int* in_sizes, int n_in,
                              void* d_out, int out_size, void* d_ws, size_t ws_size,
                              hipStream_t stream) {
    const float* x_f    = (const float*)d_in[0];
    const float* wih1_f = (const float*)d_in[1];
    const float* whh1_f = (const float*)d_in[2];
    const float* bih1   = (const float*)d_in[3];
    const float* bhh1   = (const float*)d_in[4];
    const float* wih2_f = (const float*)d_in[5];
    const float* whh2_f = (const float*)d_in[6];
    const float* bih2   = (const float*)d_in[7];
    const float* bhh2   = (const float*)d_in[8];
    const float* wl1    = (const float*)d_in[9];
    const float* bl1    = (const float*)d_in[10];
    const float* wl2    = (const float*)d_in[11];
    const float* bl2    = (const float*)d_in[12];

    uint8_t* base = (uint8_t*)d_ws;
    size_t off = 0;
    auto alloc = [&](size_t bytes) { size_t o = off; off = (off + bytes + 255) & ~(size_t)255; return o; };

    size_t pre1_off  = alloc((size_t)T_SEQ * G1 * 2);   // f16 [T,4096]
    size_t comm1_off = alloc((size_t)T_SEQ * H1 * 4);   // f32 [T,1024]
    size_t comm2_off = alloc((size_t)T_SEQ * H2 * 4);   // f32 [T,2048]
    size_t whh1_off  = alloc((size_t)G1 * H1 * 2);
    size_t whh2_off  = alloc((size_t)G2 * H2 * 2);
    size_t wih1_off  = alloc((size_t)G1 * IN_SZ * 2);
    size_t wih2_off  = alloc((size_t)G2 * H1 * 2);
    size_t xb_off    = alloc((size_t)T_SEQ * IN_SZ * 2);
    size_t p1_off    = alloc((size_t)L1OUT * 4);

    f16_t*    pre1  = (f16_t*)(base + pre1_off);
    uint32_t* comm1 = (uint32_t*)(base + comm1_off);
    uint32_t* comm2 = (uint32_t*)(base + comm2_off);
    ushort_t* whh1h = (ushort_t*)(base + whh1_off);
    ushort_t* whh2h = (ushort_t*)(base + whh2_off);
    f16_t*    wih1h = (f16_t*)(base + wih1_off);
    ushort_t* wih2h = (ushort_t*)(base + wih2_off);
    f16_t*    xb    = (f16_t*)(base + xb_off);
    float*    p1    = (float*)(base + p1_off);

    // poison sentinel comm buffers (data-as-signal)
    (void)hipMemsetAsync(comm1, 0xAA, (size_t)T_SEQ * H1 * 4, stream);
    (void)hipMemsetAsync(comm2, 0xAA, (size_t)T_SEQ * H2 * 4, stream);

    // f32 -> f16 conversions
    cvt_f16_kernel<<<2048, 256, 0, stream>>>(x_f,    xb,            T_SEQ * IN_SZ);
    cvt_f16_kernel<<<2048, 256, 0, stream>>>(wih1_f, wih1h,         G1 * IN_SZ);
    cvt_f16_kernel<<<2048, 256, 0, stream>>>(whh1_f, (f16_t*)whh1h, G1 * H1);
    cvt_f16_kernel<<<2048, 256, 0, stream>>>(wih2_f, (f16_t*)wih2h, G2 * H1);
    cvt_f16_kernel<<<4096, 256, 0, stream>>>(whh2_f, (f16_t*)whh2h, G2 * H2);

    // pre1 = x @ wih1^T + (bih1 + bhh1)   [f16 out]
    {
        dim3 grid(G1 / 64, T_SEQ / 64);
        gemm_bt_kernel<<<grid, 256, 0, stream>>>(xb, wih1h, pre1, bih1, bhh1,
                                                 T_SEQ, G1, IN_SZ);
    }

    // fused 2-layer recurrence: 256 blocks, 140KB dynamic LDS
    {
        size_t shmem = (size_t)(16 * 512 + 32 * 512 + 8 * 1024 + 2 * 512 + 2 * 1024) * 4;
        fused_lstm_kernel<<<256, 256, shmem, stream>>>(
            pre1, whh1h, wih2h, whh2h, bih2, bhh2, comm1, comm2, T_SEQ);
    }

    // p1 = wl1 . h2[T-1] + bl1 ; out = wl2 . p1 + bl2
    const float* h2_last = (const float*)(comm2 + (size_t)(T_SEQ - 1) * H2);
    linear_vec_kernel<<<L1OUT / 4, 256, 0, stream>>>(wl1, bl1, h2_last, p1, L1OUT, H2);
    linear_vec_kernel<<<OUT_SZ / 4, 256, 0, stream>>>(wl2, bl2, p1, (float*)d_out, OUT_SZ, L1OUT);

    (void)in_sizes; (void)n_in; (void)out_size; (void)ws_size;
}

// Round 11
// 11125.127 us; speedup vs baseline: 2.7008x; 1.0200x over previous
//
#include <hip/hip_runtime.h>
#include <stdint.h>

typedef unsigned short ushort_t;
typedef _Float16 f16_t;
typedef __attribute__((ext_vector_type(2))) _Float16 half2;
typedef __attribute__((ext_vector_type(8))) _Float16 half8;
typedef __attribute__((ext_vector_type(4))) float f32x4;

#define T_SEQ 4096
#define IN_SZ 512
#define H1 1024
#define H2 2048
#define G1 (4*H1)   // 4096
#define G2 (4*H2)   // 8192
#define OUT_SZ 512
#define L1OUT 1024

// f16 comm sentinel = 0x7C7C (f16 NaN pattern; exp=11111, mantissa!=0).
// h = o*tanh(c) is finite in (-1,1); (f16)h can never produce this pattern ->
// data-as-signal collision-free (proven R1/R2, both passed). Poison byte 0x7C.
#define SENT_H 0x7C7Cu

__device__ __forceinline__ float f16_val(ushort_t v) {
    union { ushort_t u; _Float16 h; } x; x.u = v; return (float)x.h;
}
__device__ __forceinline__ ushort_t f16_bits(float f) {
    union { _Float16 h; ushort_t u; } x; x.h = (_Float16)f; return x.u;
}
__device__ __forceinline__ half2 u2h(uint32_t w) {
    union { uint32_t u; half2 h; } x; x.u = w; return x.h;
}
// fast gate math
__device__ __forceinline__ float fsig(float x) {
    return __builtin_amdgcn_rcpf(1.0f + __expf(-x));
}
__device__ __forceinline__ float ftanh(float x) {
    return 1.0f - 2.0f * __builtin_amdgcn_rcpf(__expf(2.0f * x) + 1.0f);
}

// 2 MACs: acc += w·h for one packed f16 pair
__device__ __forceinline__ void dot2(float& acc, uint32_t w, uint32_t h) {
#if defined(__has_builtin) && __has_builtin(__builtin_amdgcn_fdot2)
    acc = __builtin_amdgcn_fdot2(u2h(w), u2h(h), acc, false);
#else
    half2 a = u2h(w), b = u2h(h);
    acc = fmaf((float)a.x, (float)b.x, acc);
    acc = fmaf((float)a.y, (float)b.y, acc);
#endif
}
#define DOT4(ACC, W, Hv) do { dot2(ACC, (W).x, (Hv).x); dot2(ACC, (W).y, (Hv).y); \
                              dot2(ACC, (W).z, (Hv).z); dot2(ACC, (W).w, (Hv).w); } while (0)

__device__ __forceinline__ uint64_t ald64(const uint64_t* p) {
    return __hip_atomic_load(p, __ATOMIC_RELAXED, __HIP_MEMORY_SCOPE_AGENT);
}
__device__ __forceinline__ int bad16x4(uint64_t q) {
    return (int)(((uint32_t)(q & 0xFFFFu)         == SENT_H) |
                 ((uint32_t)((q >> 16) & 0xFFFFu) == SENT_H) |
                 ((uint32_t)((q >> 32) & 0xFFFFu) == SENT_H) |
                 ((uint32_t)((q >> 48) & 0xFFFFu) == SENT_H));
}
__device__ __forceinline__ void ast16(ushort_t* p, ushort_t v) {
    __hip_atomic_store(p, v, __ATOMIC_RELAXED, __HIP_MEMORY_SCOPE_AGENT);
}

// ---------------- DPP reductions (VALU pipe; R10-proven +3.3ms win) ----------------
template<int CTRL>
__device__ __forceinline__ float dpp_add(float x) {
    union { float f; int i; } s, t;
    s.f = x;
    t.i = __builtin_amdgcn_update_dpp(0, s.i, CTRL, 0xF, 0xF, true);
    return x + t.f;
}
// sum of all 64 lanes -> valid on lane 63
__device__ __forceinline__ float red64(float x) {
    x = dpp_add<0x111>(x);   // row_shr:1
    x = dpp_add<0x112>(x);   // row_shr:2
    x = dpp_add<0x114>(x);   // row_shr:4
    x = dpp_add<0x118>(x);   // row_shr:8
    x = dpp_add<0x142>(x);   // row_bcast15
    x = dpp_add<0x143>(x);   // row_bcast31 -> lane63 = total
    return x;
}
// sum of each 32-lane half -> valid on lane 31 (lower) and lane 63 (upper)
__device__ __forceinline__ float red32(float x) {
    x = dpp_add<0x111>(x);
    x = dpp_add<0x112>(x);
    x = dpp_add<0x114>(x);
    x = dpp_add<0x118>(x);
    x = dpp_add<0x142>(x);
    return x;
}
__device__ __forceinline__ float bcast_lane63(float x) {
    union { float f; int i; } s;
    s.f = x;
    s.i = __builtin_amdgcn_readlane(s.i, 63);
    return s.f;
}

// ---------------- f32 -> f16 conversion ----------------
__global__ __launch_bounds__(256) void cvt_f16_kernel(const float* __restrict__ in,
                                                      f16_t* __restrict__ out, int n) {
    int i = blockIdx.x * 256 + threadIdx.x;
    int stride = gridDim.x * 256;
    for (; i < n; i += stride) out[i] = (f16_t)in[i];
}

// ---------------- f16 MFMA GEMM: C[M,N] = A[M,K] * B[N,K]^T + bias_a + bias_b, f16 out ----------
__global__ __launch_bounds__(256) void gemm_bt_kernel(const f16_t* __restrict__ A,
                                                      const f16_t* __restrict__ B,
                                                      f16_t* __restrict__ Cb,
                                                      const float* __restrict__ bias_a,
                                                      const float* __restrict__ bias_b,
                                                      int M, int N, int K) {
    int tid  = threadIdx.x;
    int wave = tid >> 6;
    int lane = tid & 63;
    int l15  = lane & 15;
    int quad = lane >> 4;
    int m0 = blockIdx.y * 64 + wave * 16;
    int n0 = blockIdx.x * 64;

    const f16_t* pa = A + (size_t)(m0 + l15) * K + quad * 8;
    f32x4 acc[4];
    #pragma unroll
    for (int i = 0; i < 4; ++i) acc[i] = (f32x4){0.f, 0.f, 0.f, 0.f};

    for (int kc = 0; kc < K; kc += 32) {
        half8 a = *(const half8*)(pa + kc);
        #pragma unroll
        for (int nf = 0; nf < 4; ++nf) {
            const f16_t* pb = B + (size_t)(n0 + nf * 16 + l15) * K + quad * 8 + kc;
            half8 b = *(const half8*)pb;
            acc[nf] = __builtin_amdgcn_mfma_f32_16x16x32_f16(a, b, acc[nf], 0, 0, 0);
        }
    }

    int rbase = quad * 4;
    #pragma unroll
    for (int nf = 0; nf < 4; ++nf) {
        int n = n0 + nf * 16 + l15;
        float bb = bias_a[n] + bias_b[n];
        #pragma unroll
        for (int r = 0; r < 4; ++r) {
            int m = m0 + rbase + r;
            Cb[(size_t)m * N + n] = (f16_t)(acc[nf][r] + bb);
        }
    }
}

// ---------------- Fused 2-layer LSTM recurrence, split-phase pipeline ----------------
// R10 champion (11.1ms: R4 schedule + DPP reductions) with ONE change: comm buffers
// switch f32 -> f16 (sentinel 0x7C7C = f16 NaN, proven R1/R2). Per step this halves
// poll loads (comm1: 1 u64/thread, comm2: 2), halves sentinel-compare VALU work,
// DELETES the pack_f16 staging step (polled words are already the packed-f16 LDS
// format; direct uint2 stores, stride-1), and halves publish/L3-footprint bytes.
// LDS word layout unchanged (word w = elems 2w,2w+1) -> all dot code untouched.
// 256 blocks x 256 threads (1 block/CU, persistent). Block b owns h1 units [4b,4b+4),
// h2 units [8b,8b+8). Iteration s:
//   A: poll h1[s-1], stage direct; barrier A
//   B: h1[s] = gates(whh1·h1[s-1] + pre1[s]), publish f16; pre2[s-1] = wih2·h1[s-1]
//   B': poll h2[s-2], stage direct; barrier B
//   C: h2[s-1] = gates(whh2·h2[s-2] + pre2[s-1]), publish f16
// DPP reduce totals on lane63 (wave64) / lanes31,63 (per-32); gates on ln1==63 /
// ln2==31. whh2 gate0 in LDS, gates 1..3 via pre-loop load (compiler re-schedules at
// point of use; R4-verified ~free).
__global__ __launch_bounds__(256, 1) void fused_lstm_kernel(
        const f16_t* __restrict__ pre1,       // f16 [T, 4096]
        const ushort_t* __restrict__ whh1h,   // f16 bits [4096, 1024]
        const ushort_t* __restrict__ wih2h,   // f16 bits [8192, 1024]
        const ushort_t* __restrict__ whh2h,   // f16 bits [8192, 2048]
        const float* __restrict__ bih2,
        const float* __restrict__ bhh2,
        ushort_t* __restrict__ comm1,         // f16 [T, 1024], pre-poisoned 0x7C
        ushort_t* __restrict__ comm2,         // f16 [T, 2048], pre-poisoned 0x7C
        int T) {
    extern __shared__ char smem[];
    uint32_t* whh1_w = (uint32_t*)smem;             // [16][512]  f16-pair words (32KB)
    uint32_t* wih2_w = whh1_w + 16 * 512;           // [32][512]  (64KB)
    uint32_t* whh2_w = wih2_w + 32 * 512;           // [8][1024]  gate0 (32KB)
    uint32_t* h1b    = whh2_w + 8 * 1024;           // [2][512]   packed h1 (4KB)
    uint32_t* h2b    = h1b + 2 * 512;               // [2][1024]  packed h2 (8KB)

    int tid = threadIdx.x;
    int blk = blockIdx.x;
    int u1  = tid >> 6;          // h1 unit (0..3), 64 lanes
    int ln1 = tid & 63;
    int u2l = tid >> 5;          // h2 unit (0..7), 32 lanes
    int ln2 = tid & 31;
    int wv  = tid >> 6;          // wave id

    // ---- stage resident weights into LDS (f16 bytes, same layout as the global rows) ----
    #pragma unroll
    for (int i = 0; i < 8; ++i) {            // whh1: 16 rows x 128 uint4
        int idx = tid + i * 256, r = idx >> 7, ch = idx & 127;
        size_t R = (size_t)(r & 3) * H1 + blk * 4 + (r >> 2);
        *(uint4*)&whh1_w[r * 512 + ch * 4] = *(const uint4*)(whh1h + R * H1 + ch * 8);
    }
    #pragma unroll
    for (int i = 0; i < 16; ++i) {           // wih2: 32 rows x 128 uint4
        int idx = tid + i * 256, r = idx >> 7, ch = idx & 127;
        size_t R = (size_t)(r & 3) * H2 + blk * 8 + (r >> 2);
        *(uint4*)&wih2_w[r * 512 + ch * 4] = *(const uint4*)(wih2h + R * H1 + ch * 8);
    }
    #pragma unroll
    for (int i = 0; i < 8; ++i) {            // whh2 gate0: 8 rows x 256 uint4
        int idx = tid + i * 256, r = idx >> 8, ch = idx & 255;
        size_t R = (size_t)(blk * 8 + r);
        *(uint4*)&whh2_w[r * 1024 + ch * 4] = *(const uint4*)(whh2h + R * H2 + ch * 8);
    }

    // whh2 gates 1..3 (compiler schedules these at point of use in C; R4-verified ~free)
    uint4 wreg[24];
    #pragma unroll
    for (int g = 1; g < 4; ++g) {
        size_t R = (size_t)g * H2 + blk * 8 + u2l;
        #pragma unroll
        for (int j = 0; j < 8; ++j)
            wreg[(g - 1) * 8 + j] = *(const uint4*)(whh2h + R * H2 + ln2 * 8 + j * 256);
    }

    float b2g[4];
    {
        int U = blk * 8 + u2l;
        #pragma unroll
        for (int g = 0; g < 4; ++g) b2g[g] = bih2[g * H2 + U] + bhh2[g * H2 + U];
    }

    float pc[4] = {0.f, 0.f, 0.f, 0.f};
    if (ln1 == 63) {
        #pragma unroll
        for (int g = 0; g < 4; ++g)
            pc[g] = f16_val(((const ushort_t*)pre1)[(size_t)0 * G1 + g * H1 + blk * 4 + u1]);
    }

    float c1 = 0.0f;   // ln1==63
    float c2 = 0.0f;   // ln2==31

    for (int s = 0; s <= T; ++s) {
        // ---- prefetch pre1[s+1] ----
        float pn[4] = {0.f, 0.f, 0.f, 0.f};
        if (ln1 == 63) {
            int row = (s + 1 < T) ? s + 1 : T - 1;
            #pragma unroll
            for (int g = 0; g < 4; ++g)
                pn[g] = f16_val(((const ushort_t*)pre1)[(size_t)row * G1 + g * H1 + blk * 4 + u1]);
        }

        // ---- Phase A: poll h1[s-1] (one 64-bit load = 4 f16), stage direct ----
        if (s >= 1) {
            const uint64_t* s1 = (const uint64_t*)(comm1 + (size_t)(s - 1) * H1);
            uint64_t q;
            for (;;) {
                q = ald64(&s1[tid]);
                if (!bad16x4(q)) break;
                __builtin_amdgcn_s_sleep(1);
            }
            union { uint64_t q; uint2 w; } x; x.q = q;
            *(uint2*)&h1b[((s - 1) & 1) * 512 + 2 * tid] = x.w;   // words 2tid,2tid+1
        }
        __syncthreads();   // barrier A

        const uint32_t* h1p = h1b + ((s - 1) & 1) * 512;
        uint4 hA, hB;
        if (s >= 1) {
            hA = *(const uint4*)&h1p[ln1 * 4];
            hB = *(const uint4*)&h1p[ln1 * 4 + 256];
        }

        // ---- Phase B: h1[s] ----
        if (s < T) {
            float a0 = 0.f, a1 = 0.f, a2 = 0.f, a3 = 0.f;
            if (s >= 1) {
                uint4 w;
                w = *(const uint4*)&whh1_w[(u1 * 4 + 0) * 512 + ln1 * 4];       DOT4(a0, w, hA);
                w = *(const uint4*)&whh1_w[(u1 * 4 + 0) * 512 + ln1 * 4 + 256]; DOT4(a0, w, hB);
                w = *(const uint4*)&whh1_w[(u1 * 4 + 1) * 512 + ln1 * 4];       DOT4(a1, w, hA);
                w = *(const uint4*)&whh1_w[(u1 * 4 + 1) * 512 + ln1 * 4 + 256]; DOT4(a1, w, hB);
                w = *(const uint4*)&whh1_w[(u1 * 4 + 2) * 512 + ln1 * 4];       DOT4(a2, w, hA);
                w = *(const uint4*)&whh1_w[(u1 * 4 + 2) * 512 + ln1 * 4 + 256]; DOT4(a2, w, hB);
                w = *(const uint4*)&whh1_w[(u1 * 4 + 3) * 512 + ln1 * 4];       DOT4(a3, w, hA);
                w = *(const uint4*)&whh1_w[(u1 * 4 + 3) * 512 + ln1 * 4 + 256]; DOT4(a3, w, hB);
            }
            a0 = red64(a0); a1 = red64(a1); a2 = red64(a2); a3 = red64(a3);
            if (ln1 == 63) {
                float iv = fsig(pc[0] + a0);
                float fv = fsig(pc[1] + a1);
                float gv = ftanh(pc[2] + a2);
                float ov = fsig(pc[3] + a3);
                c1 = fv * c1 + iv * gv;
                float h = ov * ftanh(c1);
                ast16(&comm1[(size_t)s * H1 + blk * 4 + u1], f16_bits(h));
            }
        }

        // ---- pre2[s-1] = this block's 32 wih2 rows · h1[s-1] ----
        float pb[8];
        if (s >= 1) {
            float pv[8];
            #pragma unroll
            for (int d = 0; d < 8; ++d) pv[d] = 0.f;
            #pragma unroll
            for (int d = 0; d < 8; ++d) {
                int r = wv * 8 + d;
                uint4 w0 = *(const uint4*)&wih2_w[r * 512 + ln1 * 4];
                uint4 w1 = *(const uint4*)&wih2_w[r * 512 + ln1 * 4 + 256];
                DOT4(pv[d], w0, hA);
                DOT4(pv[d], w1, hB);
            }
            #pragma unroll
            for (int d = 0; d < 8; ++d) pb[d] = bcast_lane63(red64(pv[d]));
        }

        // ---- Phase B': poll h2[s-2] (two 64-bit loads = 8 f16), stage direct ----
        if (s >= 2) {
            const uint64_t* s2 = (const uint64_t*)(comm2 + (size_t)(s - 2) * H2);
            uint64_t qa, qb;
            for (;;) {
                qa = ald64(&s2[tid]);
                qb = ald64(&s2[tid + 256]);
                if (!(bad16x4(qa) | bad16x4(qb))) break;
                __builtin_amdgcn_s_sleep(1);
            }
            uint32_t* d = h2b + (s & 1) * 1024;
            union { uint64_t q; uint2 w; } x;
            x.q = qa; *(uint2*)&d[2 * tid] = x.w;              // words 2tid,2tid+1
            x.q = qb; *(uint2*)&d[512 + 2 * tid] = x.w;        // words 512+2tid,+1
        }
        __syncthreads();   // barrier B

        // ---- Phase C: h2[s-1] ----
        if (s >= 1) {
            float b0 = 0.f, b1 = 0.f, b2 = 0.f, b3 = 0.f;
            if (s >= 2) {
                const uint32_t* h2p = h2b + (s & 1) * 1024;
                #pragma unroll
                for (int j = 0; j < 8; ++j) {
                    uint4 hx = *(const uint4*)&h2p[ln2 * 4 + j * 128];
                    uint4 w0 = *(const uint4*)&whh2_w[u2l * 1024 + ln2 * 4 + j * 128];
                    DOT4(b0, w0, hx);
                    DOT4(b1, wreg[j], hx);
                    DOT4(b2, wreg[8 + j], hx);
                    DOT4(b3, wreg[16 + j], hx);
                }
            }
            b0 = red32(b0); b1 = red32(b1); b2 = red32(b2); b3 = red32(b3);
            if (ln2 == 31) {   // per-32 totals live on wave lanes 31 and 63
                int half = u2l & 1;
                float iv = fsig(pb[half * 4 + 0] + b2g[0] + b0);
                float fv = fsig(pb[half * 4 + 1] + b2g[1] + b1);
                float gv = ftanh(pb[half * 4 + 2] + b2g[2] + b2);
                float ov = fsig(pb[half * 4 + 3] + b2g[3] + b3);
                c2 = fv * c2 + iv * gv;
                float h = ov * ftanh(c2);
                ast16(&comm2[(size_t)(s - 1) * H2 + blk * 8 + u2l], f16_bits(h));
            }
        }

        #pragma unroll
        for (int g = 0; g < 4; ++g) pc[g] = pn[g];
    }
}

// ---------------- small matvec (f16 input vector) ----------------
__global__ __launch_bounds__(256) void linear_vec_f16_kernel(const float* __restrict__ W,
                                                             const float* __restrict__ bias,
                                                             const ushort_t* __restrict__ x,
                                                             float* __restrict__ out,
                                                             int N, int K) {
    int wave = threadIdx.x >> 6;
    int lane = threadIdx.x & 63;
    int j = blockIdx.x * 4 + wave;
    if (j >= N) return;
    const float* wr = W + (size_t)j * K;
    float s = 0.0f;
    for (int k = lane; k < K; k += 64) s += wr[k] * f16_val(x[k]);
    #pragma unroll
    for (int off = 32; off > 0; off >>= 1) s += __shfl_down(s, off, 64);
    if (lane == 0) out[j] = s + bias[j];
}

// ---------------- small matvec (f32 input vector) ----------------
__global__ __launch_bounds__(256) void linear_vec_kernel(const float* __restrict__ W,
                                                         const float* __restrict__ bias,
                                                         const float* __restrict__ x,
                                                         float* __restrict__ out,
                                                         int N, int K) {
    int wave = threadIdx.x >> 6;
    int lane = threadIdx.x & 63;
    int j = blockIdx.x * 4 + wave;
    if (j >= N) return;
    const float* wr = W + (size_t)j * K;
    float s = 0.0f;
    for (int k = lane; k < K; k += 64) s += wr[k] * x[k];
    #pragma unroll
    for (int off = 32; off > 0; off >>= 1) s += __shfl_down(s, off, 64);
    if (lane == 0) out[j] = s + bias[j];
}

extern "C" void kernel_launch(void* const* d_in, const int* in_sizes, int n_in,
                              void* d_out, int out_size, void* d_ws, size_t ws_size,
                              hipStream_t stream) {
    const float* x_f    = (const float*)d_in[0];
    const float* wih1_f = (const float*)d_in[1];
    const float* whh1_f = (const float*)d_in[2];
    const float* bih1   = (const float*)d_in[3];
    const float* bhh1   = (const float*)d_in[4];
    const float* wih2_f = (const float*)d_in[5];
    const float* whh2_f = (const float*)d_in[6];
    const float* bih2   = (const float*)d_in[7];
    const float* bhh2   = (const float*)d_in[8];
    const float* wl1    = (const float*)d_in[9];
    const float* bl1    = (const float*)d_in[10];
    const float* wl2    = (const float*)d_in[11];
    const float* bl2    = (const float*)d_in[12];

    uint8_t* base = (uint8_t*)d_ws;
    size_t off = 0;
    auto alloc = [&](size_t bytes) { size_t o = off; off = (off + bytes + 255) & ~(size_t)255; return o; };

    size_t pre1_off  = alloc((size_t)T_SEQ * G1 * 2);   // f16 [T,4096]
    size_t comm1_off = alloc((size_t)T_SEQ * H1 * 2);   // f16 [T,1024]
    size_t comm2_off = alloc((size_t)T_SEQ * H2 * 2);   // f16 [T,2048]
    size_t whh1_off  = alloc((size_t)G1 * H1 * 2);
    size_t whh2_off  = alloc((size_t)G2 * H2 * 2);
    size_t wih1_off  = alloc((size_t)G1 * IN_SZ * 2);
    size_t wih2_off  = alloc((size_t)G2 * H1 * 2);
    size_t xb_off    = alloc((size_t)T_SEQ * IN_SZ * 2);
    size_t p1_off    = alloc((size_t)L1OUT * 4);

    f16_t*    pre1  = (f16_t*)(base + pre1_off);
    ushort_t* comm1 = (ushort_t*)(base + comm1_off);
    ushort_t* comm2 = (ushort_t*)(base + comm2_off);
    ushort_t* whh1h = (ushort_t*)(base + whh1_off);
    ushort_t* whh2h = (ushort_t*)(base + whh2_off);
    f16_t*    wih1h = (f16_t*)(base + wih1_off);
    ushort_t* wih2h = (ushort_t*)(base + wih2_off);
    f16_t*    xb    = (f16_t*)(base + xb_off);
    float*    p1    = (float*)(base + p1_off);

    // poison sentinel comm buffers: byte 0x7C -> every f16 = 0x7C7C (NaN pattern)
    (void)hipMemsetAsync(comm1, 0x7C, (size_t)T_SEQ * H1 * 2, stream);
    (void)hipMemsetAsync(comm2, 0x7C, (size_t)T_SEQ * H2 * 2, stream);

    // f32 -> f16 conversions
    cvt_f16_kernel<<<2048, 256, 0, stream>>>(x_f,    xb,            T_SEQ * IN_SZ);
    cvt_f16_kernel<<<2048, 256, 0, stream>>>(wih1_f, wih1h,         G1 * IN_SZ);
    cvt_f16_kernel<<<2048, 256, 0, stream>>>(whh1_f, (f16_t*)whh1h, G1 * H1);
    cvt_f16_kernel<<<2048, 256, 0, stream>>>(wih2_f, (f16_t*)wih2h, G2 * H1);
    cvt_f16_kernel<<<4096, 256, 0, stream>>>(whh2_f, (f16_t*)whh2h, G2 * H2);

    // pre1 = x @ wih1^T + (bih1 + bhh1)   [f16 out]
    {
        dim3 grid(G1 / 64, T_SEQ / 64);
        gemm_bt_kernel<<<grid, 256, 0, stream>>>(xb, wih1h, pre1, bih1, bhh1,
                                                 T_SEQ, G1, IN_SZ);
    }

    // fused 2-layer recurrence: 256 blocks, 140KB dynamic LDS
    {
        size_t shmem = (size_t)(16 * 512 + 32 * 512 + 8 * 1024 + 2 * 512 + 2 * 1024) * 4;
        fused_lstm_kernel<<<256, 256, shmem, stream>>>(
            pre1, whh1h, wih2h, whh2h, bih2, bhh2, comm1, comm2, T_SEQ);
    }

    // p1 = wl1 . h2[T-1] + bl1 ; out = wl2 . p1 + bl2
    const ushort_t* h2_last = comm2 + (size_t)(T_SEQ - 1) * H2;
    linear_vec_f16_kernel<<<L1OUT / 4, 256, 0, stream>>>(wl1, bl1, h2_last, p1, L1OUT, H2);
    linear_vec_kernel<<<OUT_SZ / 4, 256, 0, stream>>>(wl2, bl2, p1, (float*)d_out, OUT_SZ, L1OUT);

    (void)in_sizes; (void)n_in; (void)out_size; (void)ws_size;
}